// Round 5
// baseline (349.136 us; speedup 1.0000x reference)
//
#include <hip/hip_runtime.h>
#include <hip/hip_bf16.h>
#include <hip/hip_fp16.h>

#define IN_DIM 4096
#define OUT_DIM 4096
#define HAD_SCALE_F 0.08838834764831845f   // 2^-3.5

typedef _Float16 f16x4 __attribute__((ext_vector_type(4)));
typedef _Float16 f16x8 __attribute__((ext_vector_type(8)));
typedef float    f32x4 __attribute__((ext_vector_type(4)));

// ---------------------------------------------------------------------------
// Kernel A: per-row blockwise Hadamard (FWHT over 128-blocks), scale, f32
// rowsum, convert to fp16. One block (256 thr) per row of 4096 floats.
// ---------------------------------------------------------------------------
__global__ __launch_bounds__(256)
void had_rows(const float* __restrict__ x, _Float16* __restrict__ a,
              float* __restrict__ rowsum)
{
    __shared__ float lds[IN_DIM];
    __shared__ float wsum[4];
    const int tid = threadIdx.x;
    const size_t row = blockIdx.x;
    const float* xr = x + row * IN_DIM;

    #pragma unroll
    for (int v = 0; v < 4; ++v) {
        const int idx = v * 1024 + tid * 4;
        *(float4*)&lds[idx] = *(const float4*)&xr[idx];
    }
    __syncthreads();

    #pragma unroll
    for (int s = 0; s < 7; ++s) {
        const int stride = 1 << s;
        #pragma unroll
        for (int t = 0; t < 8; ++t) {
            const int p   = t * 256 + tid;
            const int blk = p >> 6;
            const int q   = p & 63;
            const int i   = ((q & ~(stride - 1)) << 1) | (q & (stride - 1));
            const int lo  = blk * 128 + i;
            const float u  = lds[lo];
            const float v2 = lds[lo + stride];
            lds[lo]          = u + v2;
            lds[lo + stride] = u - v2;
        }
        __syncthreads();
    }

    float ssum = 0.f;
    _Float16* ar = a + row * IN_DIM;
    #pragma unroll
    for (int v = 0; v < 4; ++v) {
        const int idx = v * 1024 + tid * 4;
        const float4 f = *(const float4*)&lds[idx];
        const float e0 = f.x * HAD_SCALE_F, e1 = f.y * HAD_SCALE_F;
        const float e2 = f.z * HAD_SCALE_F, e3 = f.w * HAD_SCALE_F;
        ssum += (e0 + e1) + (e2 + e3);
        f16x4 h = { (_Float16)e0, (_Float16)e1, (_Float16)e2, (_Float16)e3 };
        *(f16x4*)&ar[idx] = h;
    }

    #pragma unroll
    for (int off = 32; off > 0; off >>= 1) ssum += __shfl_down(ssum, off, 64);
    if ((tid & 63) == 0) wsum[tid >> 6] = ssum;
    __syncthreads();
    if (tid == 0) rowsum[row] = (wsum[0] + wsum[1]) + (wsum[2] + wsum[3]);
}

// ---------------------------------------------------------------------------
// Kernel B: unpack int4 nibbles into MFMA B-fragment order:
//   wfT chunk index ((kcg*256 + nb16)*64 + lane), 8 f16 per chunk, where
//   n = nb16*16 + (lane&15), k = kcg*32 + (lane>>4)*8.
// A wave's B-fragment load is then ONE coalesced global_load_dwordx4.
// ---------------------------------------------------------------------------
__global__ __launch_bounds__(256)
void unpack_wT(const int* __restrict__ wp, _Float16* __restrict__ wfT)
{
    const int gid  = blockIdx.x * 256 + threadIdx.x;   // chunk id
    const int l    = gid & 63;
    const int nb16 = (gid >> 6) & 255;
    const int kcg  = gid >> 14;                        // 0..127
    const int n    = nb16 * 16 + (l & 15);
    const int k0   = kcg * 32 + (l >> 4) * 8;
    const int4 p   = *(const int4*)(wp + (size_t)n * (IN_DIM / 2) + (k0 >> 1));
    f16x8 o;
    o[0] = (_Float16)(p.x & 15);  o[1] = (_Float16)((p.x >> 4) & 15);
    o[2] = (_Float16)(p.y & 15);  o[3] = (_Float16)((p.y >> 4) & 15);
    o[4] = (_Float16)(p.z & 15);  o[5] = (_Float16)((p.z >> 4) & 15);
    o[6] = (_Float16)(p.w & 15);  o[7] = (_Float16)((p.w >> 4) & 15);
    *(f16x8*)(wfT + (size_t)gid * 8) = o;
}

// ---------------------------------------------------------------------------
// Kernel C: 256x256 GEMM, A via LDS (4-buffer, lead-2 staging, XOR swizzle),
// B (weights) streamed DIRECTLY from global (wfT layout) into registers.
//   y[m,n] = wscale[n]*sum_k A[m,k]*W[n,k] + wadd[n]*rowsum[m] + bias[n]
// 512 thr = 8 waves (2M x 4N), wave tile 128x64. One region per K-tile of 64:
//   {ds_read A(mq0); 4x stage A(kt+2); 8x global B(kt+1); 32 MFMA;
//    ds_read A(mq1); 32 MFMA; vmcnt(12); barrier}
// vmcnt(12) drains exactly the PREVIOUS K-tile's 12 vmem ops (issued one full
// region earlier) -> stage(kt+1) complete before its readers, no fresh stall.
// LDS traffic is A-only (~3650 cyc/iter) < MFMA floor (~4122 cyc/iter).
// ---------------------------------------------------------------------------
#define NT (IN_DIM / 64)    // 64 K-tiles

#define BAR()        asm volatile("s_barrier" ::: "memory")
#define WAIT_VM(N)   asm volatile("s_waitcnt vmcnt(" #N ")" ::: "memory")

// A LDS buffers: 4 x 32768 B (256 rows x 128 B)
#define STAGE_A(b, R, kt) __builtin_amdgcn_global_load_lds( \
    (const __attribute__((address_space(1))) void*)(sA + ((size_t)(R) << 18) + (((kt) & 63) << 6)), \
    (__attribute__((address_space(3))) void*)(smem + (b) * 32768 + (R) * 8192 + dstA), 16, 0, 0)

#define LOAD_A(b, mq) do { \
    _Pragma("unroll") for (int mi = 0; mi < 4; ++mi) { \
        afr[mi][0] = *(const f16x8*)(smem + (b)*32768 + (mq)*8192 + mi*2048 + aOffK[0]); \
        afr[mi][1] = *(const f16x8*)(smem + (b)*32768 + (mq)*8192 + mi*2048 + aOffK[1]); \
    } } while (0)

// 8 coalesced B-fragment loads for K-tile ktv (both kc halves, 4 n-blocks)
#define LOADB(dst, ktv) do { \
    const size_t kb0_ = ((size_t)((ktv) & 63) * 2 + 0) * 256; \
    const size_t kb1_ = ((size_t)((ktv) & 63) * 2 + 1) * 256; \
    _Pragma("unroll") for (int nb = 0; nb < 4; ++nb) { \
        dst[nb][0] = *(const f16x8*)(bptr + (kb0_ + nbB + nb) * 512); \
        dst[nb][1] = *(const f16x8*)(bptr + (kb1_ + nbB + nb) * 512); \
    } } while (0)

#define MFMA_Q(bfrX, mq, nq) do { \
    __builtin_amdgcn_s_setprio(1); \
    _Pragma("unroll") for (int mi = 0; mi < 4; ++mi) \
    _Pragma("unroll") for (int ni = 0; ni < 2; ++ni) \
    _Pragma("unroll") for (int kb = 0; kb < 2; ++kb) \
        acc[(mq)*4+mi][(nq)*2+ni] = __builtin_amdgcn_mfma_f32_16x16x32_f16( \
            afr[mi][kb], bfrX[(nq)*2+ni][kb], acc[(mq)*4+mi][(nq)*2+ni], 0, 0, 0); \
    __builtin_amdgcn_s_setprio(0); \
} while (0)

// One K-tile region: read buf br, stage kt+2 -> bs, load B(kt+1) -> OTH,
// consume CONS (B frags of kt, loaded one region earlier).
#define REGION(br, bs, CONS, OTH, kt) do { \
    LOAD_A(br, 0); \
    STAGE_A(bs, 0, (kt) + 2); STAGE_A(bs, 1, (kt) + 2); \
    STAGE_A(bs, 2, (kt) + 2); STAGE_A(bs, 3, (kt) + 2); \
    LOADB(OTH, (kt) + 1); \
    MFMA_Q(CONS, 0, 0); MFMA_Q(CONS, 0, 1); \
    LOAD_A(br, 1); \
    MFMA_Q(CONS, 1, 0); MFMA_Q(CONS, 1, 1); \
    WAIT_VM(12); BAR(); \
} while (0)

__global__ __launch_bounds__(512, 2)
void gemm_bg(const _Float16* __restrict__ A, const _Float16* __restrict__ wfT,
             const float* __restrict__ wscale, const float* __restrict__ wadd,
             const float* __restrict__ bias, const float* __restrict__ rowsum,
             float* __restrict__ out)
{
    __shared__ char smem[131072];

    const int tid  = threadIdx.x;
    const int lane = tid & 63;
    const int w    = tid >> 6;     // wave 0..7
    const int wm   = w >> 2;       // 0..1
    const int wn   = w & 3;        // 0..3

    // XCD-aware swizzle, n-major chunks: 32 consecutive wgs share one B panel
    // (2 MB, L2-resident per XCD).
    const int bid = blockIdx.x;
    const int wg  = (bid & 7) * 64 + (bid >> 3);
    const int n0  = (wg >> 5) * 256;   // 16 values
    const int m0  = (wg & 31) * 256;   // 32 values

    // ---- A staging (pre-swizzled source, linear LDS dest) ----
    const int rt = tid >> 3;
    const int ct = (tid & 7) ^ (rt & 7);
    const _Float16* sA = A + (size_t)(m0 + rt) * IN_DIM + ct * 8;
    const int dstA = w * 1024;

    // ---- A fragment read offsets (swizzled) ----
    const int l15 = lane & 15, g = lane >> 4, l7 = lane & 7;
    const int s0 = (g ^ l7) << 4;
    int aOffK[2];
    aOffK[0] = (wm * 128 + l15) * 128 + s0;
    aOffK[1] = (wm * 128 + l15) * 128 + (s0 ^ 64);

    // ---- B direct-from-global addressing ----
    const _Float16* bptr = wfT + (size_t)lane * 8;
    const size_t nbB = (size_t)(n0 >> 4) + wn * 4;

    f16x8 afr[4][2], bfrA[4][2], bfrB[4][2];
    f32x4 acc[8][4] = {};

    // ---- prologue: stage kt0->buf0, load B(kt0)->bfrA, stage kt1->buf1 ----
    STAGE_A(0, 0, 0); STAGE_A(0, 1, 0); STAGE_A(0, 2, 0); STAGE_A(0, 3, 0);
    LOADB(bfrA, 0);
    STAGE_A(1, 0, 1); STAGE_A(1, 1, 1); STAGE_A(1, 2, 1); STAGE_A(1, 3, 1);
    WAIT_VM(12);   // drains stage(kt0); leaves B(kt0)+stage(kt1) in flight
    BAR();

    #pragma unroll 1
    for (int it = 0; it < NT / 4; ++it) {
        const int kt = it * 4;
        REGION(0, 2, bfrA, bfrB, kt + 0);
        REGION(1, 3, bfrB, bfrA, kt + 1);
        REGION(2, 0, bfrA, bfrB, kt + 2);
        REGION(3, 1, bfrB, bfrA, kt + 3);
    }

    // ---- epilogue: dequant + rowsum*add + bias ----
    #pragma unroll
    for (int n = 0; n < 4; ++n) {
        const int col = n0 + wn * 64 + n * 16 + l15;
        const float sc = wscale[col];
        const float ad = wadd[col];
        const float bi = bias[col];
        #pragma unroll
        for (int m = 0; m < 8; ++m) {
            const int row = m0 + wm * 128 + m * 16 + g * 4;
            const float4 rs4 = *(const float4*)&rowsum[row];
            #pragma unroll
            for (int j = 0; j < 4; ++j) {
                const float rs = (j == 0) ? rs4.x : (j == 1) ? rs4.y : (j == 2) ? rs4.z : rs4.w;
                out[(size_t)(row + j) * OUT_DIM + col] = acc[m][n][j] * sc + ad * rs + bi;
            }
        }
    }
}

// ---------------------------------------------------------------------------
extern "C" void kernel_launch(void* const* d_in, const int* in_sizes, int n_in,
                              void* d_out, int out_size, void* d_ws, size_t ws_size,
                              hipStream_t stream)
{
    const float* x      = (const float*)d_in[0];
    const int*   wp     = (const int*)d_in[1];
    const float* wscale = (const float*)d_in[2];
    const float* wadd   = (const float*)d_in[3];
    const float* bias   = (const float*)d_in[4];
    float*       out    = (float*)d_out;

    const int M = in_sizes[0] / IN_DIM;   // 8192

    char* ws = (char*)d_ws;
    _Float16* wfT = (_Float16*)ws;
    const size_t wf_bytes = (size_t)OUT_DIM * IN_DIM * sizeof(_Float16);
    _Float16* af = (_Float16*)(ws + wf_bytes);
    const size_t af_bytes = (size_t)M * IN_DIM * sizeof(_Float16);
    float* rowsum = (float*)(ws + wf_bytes + af_bytes);

    // unpack weights into MFMA-fragment-ordered layout
    const int n_chunks = (IN_DIM / 32) * (OUT_DIM / 16) * 64;   // 2M chunks
    unpack_wT<<<n_chunks / 256, 256, 0, stream>>>(wp, wfT);

    had_rows<<<M, 256, 0, stream>>>(x, af, rowsum);

    gemm_bg<<<(M / 256) * (OUT_DIM / 256), 512, 0, stream>>>(
        af, wfT, wscale, wadd, bias, rowsum, out);
}

// Round 7
// 197.289 us; speedup vs baseline: 1.7697x; 1.7697x over previous
//
#include <hip/hip_runtime.h>
#include <hip/hip_bf16.h>
#include <hip/hip_fp16.h>

#define IN_DIM 4096
#define OUT_DIM 4096
#define HAD_SCALE_F 0.08838834764831845f   // 2^-3.5

typedef int   i32x4 __attribute__((ext_vector_type(4)));
typedef float f32x4 __attribute__((ext_vector_type(4)));

// ---------------------------------------------------------------------------
// Kernel A: per-row blockwise Hadamard (FWHT over 128-blocks), scale,
// per-row absmax -> symmetric int8 quantization (s_a = max/127), and
// QUANTIZED row sum rowsum[m] = s_a * sum(q) — this keeps the epilogue
// decomposition self-consistent so quant error multiplies zero-mean w_deq,
// not mean-7.5 w_int (round-6 failure mode).
// ---------------------------------------------------------------------------
__global__ __launch_bounds__(256)
void had_rows_q(const float* __restrict__ x, int* __restrict__ aq,
                float* __restrict__ rowsum, float* __restrict__ srow)
{
    __shared__ float lds[IN_DIM];
    __shared__ float wmx[4];
    __shared__ int   wqs[4];
    const int tid = threadIdx.x;
    const size_t row = blockIdx.x;
    const float* xr = x + row * IN_DIM;

    #pragma unroll
    for (int v = 0; v < 4; ++v) {
        const int idx = v * 1024 + tid * 4;
        *(float4*)&lds[idx] = *(const float4*)&xr[idx];
    }
    __syncthreads();

    #pragma unroll
    for (int s = 0; s < 7; ++s) {
        const int stride = 1 << s;
        #pragma unroll
        for (int t = 0; t < 8; ++t) {
            const int p   = t * 256 + tid;
            const int blk = p >> 6;
            const int q   = p & 63;
            const int i   = ((q & ~(stride - 1)) << 1) | (q & (stride - 1));
            const int lo  = blk * 128 + i;
            const float u  = lds[lo];
            const float v2 = lds[lo + stride];
            lds[lo]          = u + v2;
            lds[lo + stride] = u - v2;
        }
        __syncthreads();
    }

    // pass 1: scaled values + row absmax
    float e[16];
    float smax = 0.f;
    #pragma unroll
    for (int v = 0; v < 4; ++v) {
        const int idx = v * 1024 + tid * 4;
        const float4 f = *(const float4*)&lds[idx];
        e[v*4+0] = f.x * HAD_SCALE_F; e[v*4+1] = f.y * HAD_SCALE_F;
        e[v*4+2] = f.z * HAD_SCALE_F; e[v*4+3] = f.w * HAD_SCALE_F;
        smax = fmaxf(smax, fmaxf(fmaxf(fabsf(e[v*4+0]), fabsf(e[v*4+1])),
                                 fmaxf(fabsf(e[v*4+2]), fabsf(e[v*4+3]))));
    }
    #pragma unroll
    for (int off = 32; off > 0; off >>= 1)
        smax = fmaxf(smax, __shfl_down(smax, off, 64));
    if ((tid & 63) == 0) wmx[tid >> 6] = smax;
    __syncthreads();
    const float mx  = fmaxf(fmaxf(wmx[0], wmx[1]), fmaxf(wmx[2], wmx[3]));
    const float inv = (mx > 0.f) ? 127.0f / mx : 0.f;
    const float sa  = mx * (1.0f / 127.0f);

    // pass 2: quantize, pack, accumulate integer row sum of q
    int qsum = 0;
    #pragma unroll
    for (int v = 0; v < 4; ++v) {
        const int idx = v * 1024 + tid * 4;
        const int q0 = (int)rintf(e[v*4+0] * inv);
        const int q1 = (int)rintf(e[v*4+1] * inv);
        const int q2 = (int)rintf(e[v*4+2] * inv);
        const int q3 = (int)rintf(e[v*4+3] * inv);
        qsum += (q0 + q1) + (q2 + q3);
        aq[(row * IN_DIM + idx) >> 2] =
            (q0 & 0xFF) | ((q1 & 0xFF) << 8) | ((q2 & 0xFF) << 16) | (q3 << 24);
    }
    #pragma unroll
    for (int off = 32; off > 0; off >>= 1) qsum += __shfl_down(qsum, off, 64);
    if ((tid & 63) == 0) wqs[tid >> 6] = qsum;
    __syncthreads();
    if (tid == 0) {
        rowsum[row] = sa * (float)((wqs[0] + wqs[1]) + (wqs[2] + wqs[3]));
        srow[row]   = sa;
    }
}

// ---------------------------------------------------------------------------
// Kernel B: unpack int4 nibbles -> int8 weight matrix [OUT][IN] row-major.
// ---------------------------------------------------------------------------
__global__ __launch_bounds__(256)
void unpack_w8(const int* __restrict__ wp, signed char* __restrict__ wf8)
{
    const int gid = blockIdx.x * 256 + threadIdx.x;
    const int n   = gid >> 9;
    const int k0  = (gid & 511) * 8;
    const int4 p  = *(const int4*)(wp + (size_t)n * (IN_DIM / 2) + (k0 >> 1));
    const unsigned lo = (unsigned)(p.x & 15) | ((unsigned)((p.x >> 4) & 15) << 8)
                      | ((unsigned)(p.y & 15) << 16) | ((unsigned)((p.y >> 4) & 15) << 24);
    const unsigned hi = (unsigned)(p.z & 15) | ((unsigned)((p.z >> 4) & 15) << 8)
                      | ((unsigned)(p.w & 15) << 16) | ((unsigned)((p.w >> 4) & 15) << 24);
    *(uint2*)(wf8 + (size_t)n * IN_DIM + k0) = make_uint2(lo, hi);
}

// ---------------------------------------------------------------------------
// Kernel C: 256x256 int8 GEMM, register-pipelined 8-phase schedule.
//   acc_i32[m,n] = sum_k aq[m,k]*w_int[n,k]  (exact)
//   y = srow[m]*wscale[n]*acc + wadd[n]*rowsum[m] + bias[n]
// K-region = 128 i8 = 128 B/row (byte-identical geometry to round 4's
// 64xf16). mfma_i32_16x16x64_i8, 2 k-steps/region, NT=32, NI=16.
// Same XOR swizzle (0-conflict), one barrier/phase, vmcnt(4) at P4/P8 start.
// ---------------------------------------------------------------------------
#define NT (IN_DIM / 128)   // 32 K-regions
#define NI (NT / 2)         // 16 iterations, 2 regions each

#define BAR()        asm volatile("s_barrier" ::: "memory")
#define WAIT_VM(N)   asm volatile("s_waitcnt vmcnt(" #N ")" ::: "memory")

// LDS: A0 @ 0, B0 @ 32768, A1 @ 65536, B1 @ 98304 (each 32 KiB = 256 rows x 128 B)
#define STAGE_A(p, R, kt) __builtin_amdgcn_global_load_lds( \
    (const __attribute__((address_space(1))) void*)(sA + (((size_t)(R)) << 18) + (((size_t)((kt) & 31)) << 7)), \
    (__attribute__((address_space(3))) void*)(smem + (p) * 65536 + (R) * 8192 + dstA), 16, 0, 0)
#define STAGE_B(p, R, kt) __builtin_amdgcn_global_load_lds( \
    (const __attribute__((address_space(1))) void*)(sB + (((size_t)(R)) << 18) + (((size_t)((kt) & 31)) << 7)), \
    (__attribute__((address_space(3))) void*)(smem + (p) * 65536 + (R) * 8192 + dstB), 16, 0, 0)

#define LDA(p, mq, mi, kb) (*(const i32x4*)(smem + (p)*65536 + (mq)*8192 + (mi)*2048 + aOffK[kb]))
#define LDB(p, nq, ni, kb) (*(const i32x4*)(smem + (p)*65536 + (nq)*4096 + (ni)*2048 + bOffK[kb]))

#define LOAD_A_TO(dst, p, mq) do { \
    _Pragma("unroll") for (int mi = 0; mi < 4; ++mi) { \
        dst[mi][0] = LDA(p, mq, mi, 0); \
        dst[mi][1] = LDA(p, mq, mi, 1); \
    } } while (0)

#define LOAD_B(p, nq) do { \
    _Pragma("unroll") for (int ni = 0; ni < 2; ++ni) { \
        bfr[(nq)*2+ni][0] = LDB(p, nq, ni, 0); \
        bfr[(nq)*2+ni][1] = LDB(p, nq, ni, 1); \
    } } while (0)

#define MFMA_Q(abuf, mq, nq) do { \
    __builtin_amdgcn_s_setprio(1); \
    _Pragma("unroll") for (int mi = 0; mi < 4; ++mi) \
    _Pragma("unroll") for (int ni = 0; ni < 2; ++ni) \
    _Pragma("unroll") for (int kb = 0; kb < 2; ++kb) \
        acc[(mq)*4+mi][(nq)*2+ni] = __builtin_amdgcn_mfma_i32_16x16x64_i8( \
            abuf[mi][kb], bfr[(nq)*2+ni][kb], acc[(mq)*4+mi][(nq)*2+ni], 0, 0, 0); \
    __builtin_amdgcn_s_setprio(0); \
} while (0)

__global__ __launch_bounds__(512, 2)
void gemm_i8(const signed char* __restrict__ Aq, const signed char* __restrict__ Bw,
             const float* __restrict__ wscale, const float* __restrict__ wadd,
             const float* __restrict__ bias, const float* __restrict__ rowsum,
             const float* __restrict__ srow, float* __restrict__ out)
{
    __shared__ char smem[131072];

    const int tid  = threadIdx.x;
    const int lane = tid & 63;
    const int w    = tid >> 6;     // wave 0..7
    const int wm   = w >> 2;       // 0..1
    const int wn   = w & 3;        // 0..3

    // XCD-aware bijective swizzle: 512 wgs, 8 XCDs, 64 per XCD
    const int bid = blockIdx.x;
    const int wg  = (bid & 7) * 64 + (bid >> 3);
    const int m0  = (wg >> 4) * 256;   // M/256 = 32
    const int n0  = (wg & 15) * 256;   // N/256 = 16

    // ---- staging addresses (pre-swizzled source, linear LDS dest) ----
    const int rt = tid >> 3;
    const int ct = (tid & 7) ^ (rt & 7);
    const signed char* sA = Aq + (size_t)(m0 + rt) * IN_DIM + ct * 16;
    const signed char* sB = Bw + (size_t)(n0 + rt) * IN_DIM + ct * 16;
    const int dstA = w * 1024;
    const int dstB = 32768 + w * 1024;

    // ---- fragment read offsets (swizzled) ----
    const int l15 = lane & 15, g = lane >> 4, l7 = lane & 7;
    const int s0 = (g ^ l7) << 4;
    int aOffK[2], bOffK[2];
    aOffK[0] = (wm * 128 + l15) * 128 + s0;
    aOffK[1] = (wm * 128 + l15) * 128 + (s0 ^ 64);
    bOffK[0] = 32768 + (wn * 64 + l15) * 128 + s0;
    bOffK[1] = 32768 + (wn * 64 + l15) * 128 + (s0 ^ 64);

    i32x4 afrA[4][2], afrB[4][2], bfr[4][2];
    i32x4 acc[8][4] = {};

    // ---- prologue: region0 -> buf0, region1 -> buf1 ----
    #pragma unroll
    for (int R = 0; R < 4; ++R) { STAGE_A(0, R, 0); STAGE_B(0, R, 0); }
    #pragma unroll
    for (int R = 0; R < 4; ++R) { STAGE_A(1, R, 1); STAGE_B(1, R, 1); }
    WAIT_VM(8);
    BAR();
    LOAD_B(0, 0);
    LOAD_A_TO(afrA, 0, 0);

    #pragma unroll 1
    for (int it = 0; it < NI; ++it) {
        const int kt1 = 2 * it + 1;
        const int kt2 = (2 * it + 2) & (NT - 1);
        const int kt3 = (2 * it + 3) & (NT - 1);

        // P1: MFMA Q(0,0)b0 [afrA] | read B(b0,nq1) | stage b1.B r2,3 (kt1)
        LOAD_B(0, 1);
        if (it) { STAGE_B(1, 2, kt1); STAGE_B(1, 3, kt1); }
        MFMA_Q(afrA, 0, 0);
        BAR();

        // P2: MFMA Q(0,1)b0 [afrA] | read A(b0,mq1)->afrB | stage b0.A r0,2 (kt2)
        LOAD_A_TO(afrB, 0, 1);
        STAGE_A(0, 0, kt2); STAGE_A(0, 2, kt2);
        MFMA_Q(afrA, 0, 1);
        BAR();

        // P3: MFMA Q(1,0)b0 [afrB] | stage b0.B r0,1 (kt2)
        STAGE_B(0, 0, kt2); STAGE_B(0, 1, kt2);
        MFMA_Q(afrB, 1, 0);
        BAR();

        // P4: vmcnt(4) | read B(b1,nq0)+A(b1,mq0)->afrA | stage b0.A r1,3 | MFMA Q(1,1)b0
        WAIT_VM(4);
        LOAD_B(1, 0);
        LOAD_A_TO(afrA, 1, 0);
        STAGE_A(0, 1, kt2); STAGE_A(0, 3, kt2);
        MFMA_Q(afrB, 1, 1);
        BAR();

        // P5: MFMA Q(0,0)b1 [afrA] | read B(b1,nq1) | stage b0.B r2,3 (kt2)
        LOAD_B(1, 1);
        STAGE_B(0, 2, kt2); STAGE_B(0, 3, kt2);
        MFMA_Q(afrA, 0, 0);
        BAR();

        // P6: MFMA Q(0,1)b1 [afrA] | read A(b1,mq1)->afrB | stage b1.A r0,2 (kt3)
        LOAD_A_TO(afrB, 1, 1);
        STAGE_A(1, 0, kt3); STAGE_A(1, 2, kt3);
        MFMA_Q(afrA, 0, 1);
        BAR();

        // P7: MFMA Q(1,0)b1 [afrB] | stage b1.B r0,1 (kt3)
        STAGE_B(1, 0, kt3); STAGE_B(1, 1, kt3);
        MFMA_Q(afrB, 1, 0);
        BAR();

        // P8: vmcnt(4) | read B(b0',nq0)+A(b0',mq0)->afrA | stage b1.A r1,3 | MFMA Q(1,1)b1
        WAIT_VM(4);
        LOAD_B(0, 0);
        LOAD_A_TO(afrA, 0, 0);
        STAGE_A(1, 1, kt3); STAGE_A(1, 3, kt3);
        MFMA_Q(afrB, 1, 1);
        BAR();
    }

    // ---- epilogue: y = srow[m]*wscale[n]*acc + wadd[n]*rowsum[m] + bias[n] ----
    #pragma unroll
    for (int n = 0; n < 4; ++n) {
        const int col = n0 + wn * 64 + n * 16 + l15;
        const float sc = wscale[col];
        const float ad = wadd[col];
        const float bi = bias[col];
        #pragma unroll
        for (int m = 0; m < 8; ++m) {
            const int row = m0 + wm * 128 + m * 16 + g * 4;
            const float4 rs4 = *(const float4*)&rowsum[row];
            const float4 sr4 = *(const float4*)&srow[row];
            #pragma unroll
            for (int j = 0; j < 4; ++j) {
                const float rs = (j == 0) ? rs4.x : (j == 1) ? rs4.y : (j == 2) ? rs4.z : rs4.w;
                const float sr = (j == 0) ? sr4.x : (j == 1) ? sr4.y : (j == 2) ? sr4.z : sr4.w;
                out[(size_t)(row + j) * OUT_DIM + col] =
                    (float)acc[m][n][j] * (sc * sr) + ad * rs + bi;
            }
        }
    }
}

// ---------------------------------------------------------------------------
extern "C" void kernel_launch(void* const* d_in, const int* in_sizes, int n_in,
                              void* d_out, int out_size, void* d_ws, size_t ws_size,
                              hipStream_t stream)
{
    const float* x      = (const float*)d_in[0];
    const int*   wp     = (const int*)d_in[1];
    const float* wscale = (const float*)d_in[2];
    const float* wadd   = (const float*)d_in[3];
    const float* bias   = (const float*)d_in[4];
    float*       out    = (float*)d_out;

    const int M = in_sizes[0] / IN_DIM;   // 8192

    // ws layout: [ wf8 i8 N*K | aq i8 M*K | rowsum f32 M | srow f32 M ]
    char* ws = (char*)d_ws;
    signed char* wf8 = (signed char*)ws;
    const size_t wf_bytes = (size_t)OUT_DIM * IN_DIM;
    int* aq = (int*)(ws + wf_bytes);
    const size_t aq_bytes = (size_t)M * IN_DIM;
    float* rowsum = (float*)(ws + wf_bytes + aq_bytes);
    float* srow   = (float*)(ws + wf_bytes + aq_bytes + (size_t)M * 4);

    const int unpack_blocks = (OUT_DIM * (IN_DIM / 8)) / 256;   // 8192
    unpack_w8<<<unpack_blocks, 256, 0, stream>>>(wp, wf8);

    had_rows_q<<<M, 256, 0, stream>>>(x, aq, rowsum, srow);

    gemm_i8<<<(M / 256) * (OUT_DIM / 256), 512, 0, stream>>>(
        (const signed char*)aq, wf8, wscale, wadd, bias, rowsum, srow, out);
}

// Round 8
// 194.689 us; speedup vs baseline: 1.7933x; 1.0134x over previous
//
#include <hip/hip_runtime.h>
#include <hip/hip_bf16.h>
#include <hip/hip_fp16.h>

#define IN_DIM 4096
#define OUT_DIM 4096
#define HAD_SCALE_F 0.08838834764831845f   // 2^-3.5

typedef int   i32x4 __attribute__((ext_vector_type(4)));
typedef float f32x4 __attribute__((ext_vector_type(4)));

// ---------------------------------------------------------------------------
// Kernel A: per-row blockwise Hadamard (FWHT over 128-blocks), scale,
// per-row absmax -> symmetric int8 quantization (s_a = max/127), and
// QUANTIZED row sum rowsum[m] = s_a * sum(q) (keeps epilogue decomposition
// self-consistent: quant error multiplies zero-mean w_deq).
// ---------------------------------------------------------------------------
__global__ __launch_bounds__(256)
void had_rows_q(const float* __restrict__ x, int* __restrict__ aq,
                float* __restrict__ rowsum, float* __restrict__ srow)
{
    __shared__ float lds[IN_DIM];
    __shared__ float wmx[4];
    __shared__ int   wqs[4];
    const int tid = threadIdx.x;
    const size_t row = blockIdx.x;
    const float* xr = x + row * IN_DIM;

    #pragma unroll
    for (int v = 0; v < 4; ++v) {
        const int idx = v * 1024 + tid * 4;
        *(float4*)&lds[idx] = *(const float4*)&xr[idx];
    }
    __syncthreads();

    #pragma unroll
    for (int s = 0; s < 7; ++s) {
        const int stride = 1 << s;
        #pragma unroll
        for (int t = 0; t < 8; ++t) {
            const int p   = t * 256 + tid;
            const int blk = p >> 6;
            const int q   = p & 63;
            const int i   = ((q & ~(stride - 1)) << 1) | (q & (stride - 1));
            const int lo  = blk * 128 + i;
            const float u  = lds[lo];
            const float v2 = lds[lo + stride];
            lds[lo]          = u + v2;
            lds[lo + stride] = u - v2;
        }
        __syncthreads();
    }

    float e[16];
    float smax = 0.f;
    #pragma unroll
    for (int v = 0; v < 4; ++v) {
        const int idx = v * 1024 + tid * 4;
        const float4 f = *(const float4*)&lds[idx];
        e[v*4+0] = f.x * HAD_SCALE_F; e[v*4+1] = f.y * HAD_SCALE_F;
        e[v*4+2] = f.z * HAD_SCALE_F; e[v*4+3] = f.w * HAD_SCALE_F;
        smax = fmaxf(smax, fmaxf(fmaxf(fabsf(e[v*4+0]), fabsf(e[v*4+1])),
                                 fmaxf(fabsf(e[v*4+2]), fabsf(e[v*4+3]))));
    }
    #pragma unroll
    for (int off = 32; off > 0; off >>= 1)
        smax = fmaxf(smax, __shfl_down(smax, off, 64));
    if ((tid & 63) == 0) wmx[tid >> 6] = smax;
    __syncthreads();
    const float mx  = fmaxf(fmaxf(wmx[0], wmx[1]), fmaxf(wmx[2], wmx[3]));
    const float inv = (mx > 0.f) ? 127.0f / mx : 0.f;
    const float sa  = mx * (1.0f / 127.0f);

    int qsum = 0;
    #pragma unroll
    for (int v = 0; v < 4; ++v) {
        const int idx = v * 1024 + tid * 4;
        const int q0 = (int)rintf(e[v*4+0] * inv);
        const int q1 = (int)rintf(e[v*4+1] * inv);
        const int q2 = (int)rintf(e[v*4+2] * inv);
        const int q3 = (int)rintf(e[v*4+3] * inv);
        qsum += (q0 + q1) + (q2 + q3);
        aq[(row * IN_DIM + idx) >> 2] =
            (q0 & 0xFF) | ((q1 & 0xFF) << 8) | ((q2 & 0xFF) << 16) | (q3 << 24);
    }
    #pragma unroll
    for (int off = 32; off > 0; off >>= 1) qsum += __shfl_down(qsum, off, 64);
    if ((tid & 63) == 0) wqs[tid >> 6] = qsum;
    __syncthreads();
    if (tid == 0) {
        rowsum[row] = sa * (float)((wqs[0] + wqs[1]) + (wqs[2] + wqs[3]));
        srow[row]   = sa;
    }
}

// ---------------------------------------------------------------------------
// Kernel B: unpack int4 nibbles -> int8 weight matrix [OUT][IN] row-major.
// ---------------------------------------------------------------------------
__global__ __launch_bounds__(256)
void unpack_w8(const int* __restrict__ wp, signed char* __restrict__ wf8)
{
    const int gid = blockIdx.x * 256 + threadIdx.x;
    const int n   = gid >> 9;
    const int k0  = (gid & 511) * 8;
    const int4 p  = *(const int4*)(wp + (size_t)n * (IN_DIM / 2) + (k0 >> 1));
    const unsigned lo = (unsigned)(p.x & 15) | ((unsigned)((p.x >> 4) & 15) << 8)
                      | ((unsigned)(p.y & 15) << 16) | ((unsigned)((p.y >> 4) & 15) << 24);
    const unsigned hi = (unsigned)(p.z & 15) | ((unsigned)((p.z >> 4) & 15) << 8)
                      | ((unsigned)(p.w & 15) << 16) | ((unsigned)((p.w >> 4) & 15) << 24);
    *(uint2*)(wf8 + (size_t)n * IN_DIM + k0) = make_uint2(lo, hi);
}

// ---------------------------------------------------------------------------
// Kernel C: 256x256 int8 GEMM, 4-WINDOW schedule (round-8 change).
// Round 7 had 8 barriers/iter: all 8 waves lockstep -> per phase the 96-b128
// LDS burst (768cy) and the MFMA burst (653cy) alternate serially. Merging
// phases into 4 windows (barrier at end of each) lets waves drift and the
// LDS pipe fill MFMA gaps. Ledger (A-halves h0={R0,R2} h1={R1,R3}; B nqX
// touches X-halves of all rounds):
//   reads:  b0: W4(h0,nq0) W1(nq1,h1)   b1: W2(h0,nq0) W3(nq1,h1)
//   stages: W1: b1{Br2,r3; Ar1,r3}(kt1)  W2: b0{Br0,r1; Ar0,r2}(kt2)
//           W3: b0{Br2,r3; Ar1,r3}(kt2)  W4: b1{Br0,r1; Ar0,r2}(kt3)
//   every stage >=1 barrier after its rounds' last reader; vmcnt BEFORE each
//   barrier (strict drain->barrier->read ordering, fixing round-7's
//   time-based cross-wave hazard): W1:vm(2) W2:vm(4) W3:vm(2) W4:vm(4).
// ---------------------------------------------------------------------------
#define NT (IN_DIM / 128)   // 32 K-regions
#define NI (NT / 2)         // 16 iterations, 2 regions each

#define BAR()        asm volatile("s_barrier" ::: "memory")
#define WAIT_VM(N)   asm volatile("s_waitcnt vmcnt(" #N ")" ::: "memory")

// LDS: A0 @ 0, B0 @ 32768, A1 @ 65536, B1 @ 98304 (each 32 KiB = 256 rows x 128 B)
#define STAGE_A(p, R, kt) __builtin_amdgcn_global_load_lds( \
    (const __attribute__((address_space(1))) void*)(sA + (((size_t)(R)) << 18) + (((size_t)((kt) & 31)) << 7)), \
    (__attribute__((address_space(3))) void*)(smem + (p) * 65536 + (R) * 8192 + dstA), 16, 0, 0)
#define STAGE_B(p, R, kt) __builtin_amdgcn_global_load_lds( \
    (const __attribute__((address_space(1))) void*)(sB + (((size_t)(R)) << 18) + (((size_t)((kt) & 31)) << 7)), \
    (__attribute__((address_space(3))) void*)(smem + (p) * 65536 + (R) * 8192 + dstB), 16, 0, 0)

#define LDA(p, mq, mi, kb) (*(const i32x4*)(smem + (p)*65536 + (mq)*8192 + (mi)*2048 + aOffK[kb]))
#define LDB(p, nq, ni, kb) (*(const i32x4*)(smem + (p)*65536 + (nq)*4096 + (ni)*2048 + bOffK[kb]))

#define LOAD_A_TO(dst, p, mq) do { \
    _Pragma("unroll") for (int mi = 0; mi < 4; ++mi) { \
        dst[mi][0] = LDA(p, mq, mi, 0); \
        dst[mi][1] = LDA(p, mq, mi, 1); \
    } } while (0)

#define LOAD_B(p, nq) do { \
    _Pragma("unroll") for (int ni = 0; ni < 2; ++ni) { \
        bfr[(nq)*2+ni][0] = LDB(p, nq, ni, 0); \
        bfr[(nq)*2+ni][1] = LDB(p, nq, ni, 1); \
    } } while (0)

#define MFMA_Q(abuf, mq, nq) do { \
    __builtin_amdgcn_s_setprio(1); \
    _Pragma("unroll") for (int mi = 0; mi < 4; ++mi) \
    _Pragma("unroll") for (int ni = 0; ni < 2; ++ni) \
    _Pragma("unroll") for (int kb = 0; kb < 2; ++kb) \
        acc[(mq)*4+mi][(nq)*2+ni] = __builtin_amdgcn_mfma_i32_16x16x64_i8( \
            abuf[mi][kb], bfr[(nq)*2+ni][kb], acc[(mq)*4+mi][(nq)*2+ni], 0, 0, 0); \
    __builtin_amdgcn_s_setprio(0); \
} while (0)

__global__ __launch_bounds__(512, 2)
void gemm_i8(const signed char* __restrict__ Aq, const signed char* __restrict__ Bw,
             const float* __restrict__ wscale, const float* __restrict__ wadd,
             const float* __restrict__ bias, const float* __restrict__ rowsum,
             const float* __restrict__ srow, float* __restrict__ out)
{
    __shared__ char smem[131072];

    const int tid  = threadIdx.x;
    const int lane = tid & 63;
    const int w    = tid >> 6;     // wave 0..7
    const int wm   = w >> 2;       // 0..1
    const int wn   = w & 3;        // 0..3

    // XCD-aware bijective swizzle: 512 wgs, 8 XCDs, 64 per XCD
    const int bid = blockIdx.x;
    const int wg  = (bid & 7) * 64 + (bid >> 3);
    const int m0  = (wg >> 4) * 256;   // M/256 = 32
    const int n0  = (wg & 15) * 256;   // N/256 = 16

    // ---- staging addresses (pre-swizzled source, linear LDS dest) ----
    const int rt = tid >> 3;
    const int ct = (tid & 7) ^ (rt & 7);
    const signed char* sA = Aq + (size_t)(m0 + rt) * IN_DIM + ct * 16;
    const signed char* sB = Bw + (size_t)(n0 + rt) * IN_DIM + ct * 16;
    const int dstA = w * 1024;
    const int dstB = 32768 + w * 1024;

    // ---- fragment read offsets (swizzled) ----
    const int l15 = lane & 15, g = lane >> 4, l7 = lane & 7;
    const int s0 = (g ^ l7) << 4;
    int aOffK[2], bOffK[2];
    aOffK[0] = (wm * 128 + l15) * 128 + s0;
    aOffK[1] = (wm * 128 + l15) * 128 + (s0 ^ 64);
    bOffK[0] = 32768 + (wn * 64 + l15) * 128 + s0;
    bOffK[1] = 32768 + (wn * 64 + l15) * 128 + (s0 ^ 64);

    i32x4 afrA[4][2], afrB[4][2], bfr[4][2];
    i32x4 acc[8][4] = {};

    // ---- prologue: region0 -> buf0, region1 -> buf1 ----
    #pragma unroll
    for (int R = 0; R < 4; ++R) { STAGE_A(0, R, 0); STAGE_B(0, R, 0); }
    #pragma unroll
    for (int R = 0; R < 4; ++R) { STAGE_A(1, R, 1); STAGE_B(1, R, 1); }
    WAIT_VM(8);
    BAR();
    LOAD_B(0, 0);
    LOAD_A_TO(afrA, 0, 0);

    #pragma unroll 1
    for (int it = 0; it < NI; ++it) {
        const int kt1 = 2 * it + 1;
        const int kt2 = (2 * it + 2) & (NT - 1);
        const int kt3 = (2 * it + 3) & (NT - 1);

        // ---- W1: MFMA Q(0,0),Q(0,1) of b0 | read b0 nq1,h1 | stage b1 B r2,3 + A r1,3 (kt1)
        LOAD_B(0, 1);
        if (it) { STAGE_B(1, 2, kt1); STAGE_B(1, 3, kt1); }
        MFMA_Q(afrA, 0, 0);
        LOAD_A_TO(afrB, 0, 1);
        if (it) { STAGE_A(1, 1, kt1); STAGE_A(1, 3, kt1); }
        MFMA_Q(afrA, 0, 1);
        if (it) { WAIT_VM(2); } else { WAIT_VM(0); }
        BAR();

        // ---- W2: MFMA Q(1,0),Q(1,1) of b0 | read b1 nq0,h0 | stage b0 B r0,1 + A r0,2 (kt2)
        STAGE_B(0, 0, kt2); STAGE_B(0, 1, kt2);
        MFMA_Q(afrB, 1, 0);
        LOAD_B(1, 0);
        LOAD_A_TO(afrA, 1, 0);
        STAGE_A(0, 0, kt2); STAGE_A(0, 2, kt2);
        MFMA_Q(afrB, 1, 1);
        WAIT_VM(4);
        BAR();

        // ---- W3: MFMA Q(0,0),Q(0,1) of b1 | read b1 nq1,h1 | stage b0 B r2,3 + A r1,3 (kt2)
        STAGE_B(0, 2, kt2); STAGE_B(0, 3, kt2);
        MFMA_Q(afrA, 0, 0);
        LOAD_B(1, 1);
        LOAD_A_TO(afrB, 1, 1);
        STAGE_A(0, 1, kt2); STAGE_A(0, 3, kt2);
        MFMA_Q(afrA, 0, 1);
        WAIT_VM(2);
        BAR();

        // ---- W4: MFMA Q(1,0),Q(1,1) of b1 | read b0' nq0,h0 | stage b1 B r0,1 + A r0,2 (kt3)
        STAGE_B(1, 0, kt3); STAGE_B(1, 1, kt3);
        MFMA_Q(afrB, 1, 0);
        LOAD_B(0, 0);
        LOAD_A_TO(afrA, 0, 0);
        STAGE_A(1, 0, kt3); STAGE_A(1, 2, kt3);
        MFMA_Q(afrB, 1, 1);
        WAIT_VM(4);
        BAR();
    }

    // ---- epilogue: y = srow[m]*wscale[n]*acc + wadd[n]*rowsum[m] + bias[n] ----
    #pragma unroll
    for (int n = 0; n < 4; ++n) {
        const int col = n0 + wn * 64 + n * 16 + l15;
        const float sc = wscale[col];
        const float ad = wadd[col];
        const float bi = bias[col];
        #pragma unroll
        for (int m = 0; m < 8; ++m) {
            const int row = m0 + wm * 128 + m * 16 + g * 4;
            const float4 rs4 = *(const float4*)&rowsum[row];
            const float4 sr4 = *(const float4*)&srow[row];
            #pragma unroll
            for (int j = 0; j < 4; ++j) {
                const float rs = (j == 0) ? rs4.x : (j == 1) ? rs4.y : (j == 2) ? rs4.z : rs4.w;
                const float sr = (j == 0) ? sr4.x : (j == 1) ? sr4.y : (j == 2) ? sr4.z : sr4.w;
                out[(size_t)(row + j) * OUT_DIM + col] =
                    (float)acc[m][n][j] * (sc * sr) + ad * rs + bi;
            }
        }
    }
}

// ---------------------------------------------------------------------------
extern "C" void kernel_launch(void* const* d_in, const int* in_sizes, int n_in,
                              void* d_out, int out_size, void* d_ws, size_t ws_size,
                              hipStream_t stream)
{
    const float* x      = (const float*)d_in[0];
    const int*   wp     = (const int*)d_in[1];
    const float* wscale = (const float*)d_in[2];
    const float* wadd   = (const float*)d_in[3];
    const float* bias   = (const float*)d_in[4];
    float*       out    = (float*)d_out;

    const int M = in_sizes[0] / IN_DIM;   // 8192

    // ws layout: [ wf8 i8 N*K | aq i8 M*K | rowsum f32 M | srow f32 M ]
    char* ws = (char*)d_ws;
    signed char* wf8 = (signed char*)ws;
    const size_t wf_bytes = (size_t)OUT_DIM * IN_DIM;
    int* aq = (int*)(ws + wf_bytes);
    const size_t aq_bytes = (size_t)M * IN_DIM;
    float* rowsum = (float*)(ws + wf_bytes + aq_bytes);
    float* srow   = (float*)(ws + wf_bytes + aq_bytes + (size_t)M * 4);

    const int unpack_blocks = (OUT_DIM * (IN_DIM / 8)) / 256;   // 8192
    unpack_w8<<<unpack_blocks, 256, 0, stream>>>(wp, wf8);

    had_rows_q<<<M, 256, 0, stream>>>(x, aq, rowsum, srow);

    gemm_i8<<<(M / 256) * (OUT_DIM / 256), 512, 0, stream>>>(
        (const signed char*)aq, wf8, wscale, wadd, bias, rowsum, srow, out);
}